// Round 1
// baseline (645.355 us; speedup 1.0000x reference)
//
#include <hip/hip_runtime.h>
#include <math.h>

constexpr int S_LEN  = 256;
constexpr int T_LEN  = 2560;
constexpr int D_IN   = 512;
constexpr int DK     = 64;
constexpr int B_N    = 2;
constexpr int ROWS_A = 8;

__device__ __forceinline__ float wave_reduce_sum(float v) {
#pragma unroll
    for (int off = 32; off > 0; off >>= 1) v += __shfl_down(v, off);
    return v;
}

// ---------------------------------------------------------------------------
// Kernel A: region-wise LayerNorm + QKV projection.
// One block = ROWS_A consecutive rows (never straddles a region boundary:
// regions are multiples of 256, ROWS_A=8). Writes q,v natural (B,T,64) and
// k transposed (B,64,T) so attention pass-1 reads are coalesced.
// ---------------------------------------------------------------------------
__global__ __launch_bounds__(256) void ln_qkv_kernel(
    const float* __restrict__ x,
    const float* __restrict__ w_q,  const float* __restrict__ w_k,  const float* __restrict__ w_v,
    const float* __restrict__ w_qs, const float* __restrict__ w_ks, const float* __restrict__ w_vs,
    const float* __restrict__ w_qe, const float* __restrict__ w_ke, const float* __restrict__ w_ve,
    const float* __restrict__ g_m,  const float* __restrict__ b_m,
    const float* __restrict__ g_s,  const float* __restrict__ b_s,
    const float* __restrict__ g_e,  const float* __restrict__ b_e,
    float* __restrict__ q_out, float* __restrict__ kT_out, float* __restrict__ v_out)
{
    const int tid  = threadIdx.x;
    const int row0 = blockIdx.x * ROWS_A;
    const int b    = row0 / T_LEN;
    const int t0   = row0 % T_LEN;

    __shared__ float xn[ROWS_A][D_IN];
    __shared__ float red[8];

    const float *gv, *bv, *WQ, *WK, *WV;
    if (t0 < S_LEN)              { gv = g_s; bv = b_s; WQ = w_qs; WK = w_ks; WV = w_vs; }
    else if (t0 < T_LEN - S_LEN) { gv = g_m; bv = b_m; WQ = w_q;  WK = w_k;  WV = w_v;  }
    else                         { gv = g_e; bv = b_e; WQ = w_qe; WK = w_ke; WV = w_ve; }

    for (int r = 0; r < ROWS_A; ++r) {
        const float* xr = x + (size_t)(row0 + r) * D_IN;
        float a0 = xr[tid], a1 = xr[tid + 256];
        float s = wave_reduce_sum(a0 + a1);
        __syncthreads();
        if ((tid & 63) == 0) red[tid >> 6] = s;
        __syncthreads();
        float mean = (red[0] + red[1] + red[2] + red[3]) * (1.0f / D_IN);
        float d0 = a0 - mean, d1 = a1 - mean;
        float sq = wave_reduce_sum(d0 * d0 + d1 * d1);
        __syncthreads();
        if ((tid & 63) == 0) red[tid >> 6] = sq;
        __syncthreads();
        float var = (red[0] + red[1] + red[2] + red[3]) * (1.0f / D_IN);
        float inv = rsqrtf(var + 1e-5f);
        xn[r][tid]       = d0 * inv * gv[tid]       + bv[tid];
        xn[r][tid + 256] = d1 * inv * gv[tid + 256] + bv[tid + 256];
    }
    __syncthreads();

    if (tid < 192) {
        const int mat = tid >> 6, col = tid & 63;
        const float* W = (mat == 0) ? WQ : (mat == 1) ? WK : WV;
        float acc[ROWS_A];
#pragma unroll
        for (int r = 0; r < ROWS_A; ++r) acc[r] = 0.f;
        for (int d = 0; d < D_IN; ++d) {
            float wv = W[d * DK + col];
#pragma unroll
            for (int r = 0; r < ROWS_A; ++r) acc[r] += xn[r][d] * wv;
        }
#pragma unroll
        for (int r = 0; r < ROWS_A; ++r) {
            int row = row0 + r;
            if (mat == 0)       q_out[(size_t)row * DK + col] = acc[r];
            else if (mat == 1)  kT_out[((size_t)b * DK + col) * T_LEN + (t0 + r)] = acc[r];
            else                v_out[(size_t)row * DK + col] = acc[r];
        }
    }
}

// ---------------------------------------------------------------------------
// Kernel B: one block per (b, t) query row.
//  1. logits[s] = q.k_s and li[m] = q.cope[:,m] (coalesced over s/m, both LDS)
//  2. gates = sigmoid(logits); pos[s] = total - exclusive_prefix[s] via scan
//  3. CoPE bias by LDS gather of li at floor/ceil(pos); att = logits/8 + bias
//  4. causal softmax + PV accumulate
// ---------------------------------------------------------------------------
__global__ __launch_bounds__(256) void attn_kernel(
    const float* __restrict__ q_in,
    const float* __restrict__ kT,
    const float* __restrict__ v_in,
    const float* __restrict__ cope,
    float* __restrict__ out)
{
    const int tid = threadIdx.x;
    const int row = blockIdx.x;
    const int b   = row / T_LEN;
    const int t   = row % T_LEN;

    __shared__ float sq[DK];
    __shared__ float slog[T_LEN];
    __shared__ float sli[T_LEN];
    __shared__ float sscan[256];
    __shared__ float red[8];

    if (tid < DK) sq[tid] = q_in[(size_t)row * DK + tid];
    __syncthreads();

    const float* kTb = kT + (size_t)b * DK * T_LEN;

    // pass 1: logits + li rows
    for (int s = tid; s < T_LEN; s += 256) {
        float lg = 0.f, lm = 0.f;
#pragma unroll 16
        for (int d = 0; d < DK; ++d) {
            float qd = sq[d];
            lg += qd * kTb[d * T_LEN + s];
            lm += qd * cope[d * T_LEN + s];
        }
        slog[s] = lg;
        sli[s]  = lm;
    }
    __syncthreads();

    // gates + thread-local sums (contiguous chunks of CH)
    constexpr int CH = T_LEN / 256;  // 10
    const int s0 = tid * CH;
    float g[CH];
    float lsum = 0.f;
#pragma unroll
    for (int i = 0; i < CH; ++i) {
        float gg = 1.0f / (1.0f + __expf(-slog[s0 + i]));
        g[i] = gg;
        lsum += gg;
    }
    sscan[tid] = lsum;
    __syncthreads();
    // Hillis-Steele inclusive scan over 256 thread sums
    for (int off = 1; off < 256; off <<= 1) {
        float add = (tid >= off) ? sscan[tid - off] : 0.f;
        __syncthreads();
        sscan[tid] += add;
        __syncthreads();
    }
    const float total = sscan[255];
    float run = sscan[tid] - lsum;  // exclusive prefix of gates before s0

    // CoPE bias + causal mask; att logits in registers
    float att[CH];
    float lmax = -INFINITY;
#pragma unroll
    for (int i = 0; i < CH; ++i) {
        int s = s0 + i;
        float pos = total - run;    // sum_{s' >= s} gates
        run += g[i];
        pos = fminf(pos, (float)(T_LEN - 1));
        float pf = floorf(pos);
        float w  = pos - pf;
        int ipf  = (int)pf;
        int ipc  = (int)ceilf(pos);
        float bias = sli[ipc] * w + sli[ipf] * (1.0f - w);
        float al = slog[s] * 0.125f + bias;
        if (s > t) al = -INFINITY;
        att[i] = al;
        lmax = fmaxf(lmax, al);
    }

    // block max
#pragma unroll
    for (int off = 32; off > 0; off >>= 1) lmax = fmaxf(lmax, __shfl_down(lmax, off));
    __syncthreads();
    if ((tid & 63) == 0) red[tid >> 6] = lmax;
    __syncthreads();
    const float bmax = fmaxf(fmaxf(red[0], red[1]), fmaxf(red[2], red[3]));

    // exp + sum; probabilities back into slog
    float esum = 0.f;
#pragma unroll
    for (int i = 0; i < CH; ++i) {
        int s = s0 + i;
        float e = (s <= t) ? __expf(att[i] - bmax) : 0.f;
        slog[s] = e;
        esum += e;
    }
#pragma unroll
    for (int off = 32; off > 0; off >>= 1) esum += __shfl_down(esum, off);
    __syncthreads();
    if ((tid & 63) == 0) red[4 + (tid >> 6)] = esum;
    __syncthreads();
    const float rdenom = 1.0f / (red[4] + red[5] + red[6] + red[7]);

    // PV: out[d] = (1/denom) * sum_s p[s] * v[s][d]
    const int d   = tid & 63;
    const int grp = tid >> 6;
    const float* vb = v_in + (size_t)b * T_LEN * DK;
    float acc = 0.f;
    for (int s = grp; s <= t; s += 4) {
        acc += slog[s] * vb[(size_t)s * DK + d];
    }
    sscan[tid] = acc;
    __syncthreads();
    if (grp == 0) {
        acc += sscan[tid + 64] + sscan[tid + 128] + sscan[tid + 192];
        out[(size_t)row * DK + d] = acc * rdenom;
    }
}

extern "C" void kernel_launch(void* const* d_in, const int* in_sizes, int n_in,
                              void* d_out, int out_size, void* d_ws, size_t ws_size,
                              hipStream_t stream)
{
    const float* x    = (const float*)d_in[0];
    const float* w_q  = (const float*)d_in[1];
    const float* w_k  = (const float*)d_in[2];
    const float* w_v  = (const float*)d_in[3];
    const float* w_qs = (const float*)d_in[4];
    const float* w_ks = (const float*)d_in[5];
    const float* w_vs = (const float*)d_in[6];
    const float* w_qe = (const float*)d_in[7];
    const float* w_ke = (const float*)d_in[8];
    const float* w_ve = (const float*)d_in[9];
    const float* g_m  = (const float*)d_in[10];
    const float* b_m  = (const float*)d_in[11];
    const float* g_s  = (const float*)d_in[12];
    const float* b_s  = (const float*)d_in[13];
    const float* g_e  = (const float*)d_in[14];
    const float* b_e  = (const float*)d_in[15];
    const float* cope = (const float*)d_in[16];

    float* q_ws  = (float*)d_ws;
    float* kT_ws = q_ws  + (size_t)B_N * T_LEN * DK;
    float* v_ws  = kT_ws + (size_t)B_N * T_LEN * DK;

    ln_qkv_kernel<<<(B_N * T_LEN) / ROWS_A, 256, 0, stream>>>(
        x, w_q, w_k, w_v, w_qs, w_ks, w_vs, w_qe, w_ke, w_ve,
        g_m, b_m, g_s, b_s, g_e, b_e,
        q_ws, kT_ws, v_ws);

    attn_kernel<<<B_N * T_LEN, 256, 0, stream>>>(q_ws, kT_ws, v_ws, cope, (float*)d_out);
}